// Round 13
// baseline (98.253 us; speedup 1.0000x reference)
//
#include <hip/hip_runtime.h>
#include <math.h>

#define EPSV 1e-12f

typedef __attribute__((ext_vector_type(8))) short short8;
typedef __attribute__((ext_vector_type(4))) float f32x4;

constexpr int MT    = 10;            // m-tiles of 16 -> K_PAD = 160
constexpr int K_PAD = 160;
constexpr int CPB   = 64;            // channels per block (4 ct tiles)
constexpr int CGN   = 4;             // channel groups
constexpr int CHUNK = 128;           // pixels per staged chunk (4 ksteps)
constexpr int PBPX  = 512;           // pixels per strip
constexpr int NCHK  = PBPX / CHUNK;  // 4 chunks
constexpr int NPB   = 256;           // strips
constexpr int THR   = 512;           // 8 waves
constexpr int LROW  = 136;           // LDS B-row stride in shorts

// ---------------------------------------------------------------------------
// protomm: one-hot MFMA GEMM, r8's proven memory engine (reg-staged flat
// loads, 4 blocks/CU, 1 barrier/chunk) + cvt_pk commit + ctg/mg wave map
// (A-frag shared by 2 MFMAs) + bf16 block-private linear flush (no RMW).
// ---------------------------------------------------------------------------
__global__ __launch_bounds__(THR, 8) void protomm_kernel(
    const float* __restrict__ feat,      // [B,C,HW]
    const int*   __restrict__ labels,    // [B,HW]
    const int*   __restrict__ ign_p,
    unsigned short* __restrict__ partial16, // [NPB][CGN][2][K_PAD][32] bf16
    float*       __restrict__ vmask,     // [K_PAD] pre-zeroed
    int C, int HW)
{
    __shared__ unsigned short Bf[2][CPB * LROW];   // 34.8 KB (reused by flush)
    __shared__ int   labL[PBPX];                   // 2 KB
    __shared__ unsigned char pres[K_PAD];

    const int tid   = threadIdx.x;
    const int w     = tid >> 6;
    const int lane  = tid & 63;
    const int rowid = lane & 15;
    const int g     = lane >> 4;
    const int ctg   = w & 1;            // ct pair {2ctg, 2ctg+1}
    const int mg    = w >> 1;           // m in {mg, mg+4, mg+8<10}

    const int bid = blockIdx.x;
    const int cg  = bid & 3;
    const int pb  = bid >> 2;
    const int b   = pb >> 5;            // 32 strips per image
    const int px0 = (pb & 31) * PBPX;
    const int ig  = *ign_p;

    if (cg == 0)
        for (int i = tid; i < K_PAD; i += THR) pres[i] = 0;
    {
        int lv = labels[(size_t)b * HW + px0 + tid];
        labL[tid] = (lv == ig) ? 0 : lv;
    }
    __syncthreads();
    if (cg == 0) {
        int la = labL[tid];
        if ((unsigned)la < (unsigned)K_PAD) pres[la] = 1;   // benign races
    }

    const int qq  = tid & 31;
    const int chp = tid >> 5;           // 0..15
    const float* fb = feat + ((size_t)(b * C + cg * CPB + chp)) * HW + px0 + 4 * qq;

    f32x4 acc0[3], acc1[3];
    #pragma unroll
    for (int j = 0; j < 3; ++j) {
        acc0[j] = (f32x4){0.f, 0.f, 0.f, 0.f};
        acc1[j] = (f32x4){0.f, 0.f, 0.f, 0.f};
    }

    float4 pf0, pf1, pf2, pf3;
    auto issue = [&](int ck) {
        const float* p = fb + ck * CHUNK;
        pf0 = *reinterpret_cast<const float4*>(p);
        pf1 = *reinterpret_cast<const float4*>(p + (size_t)16 * HW);
        pf2 = *reinterpret_cast<const float4*>(p + (size_t)32 * HW);
        pf3 = *reinterpret_cast<const float4*>(p + (size_t)48 * HW);
    };
    auto commit = [&](int buf) {
        float4 v[4] = {pf0, pf1, pf2, pf3};
        #pragma unroll
        for (int i = 0; i < 4; ++i) {
            unsigned u0, u1;
            asm("v_cvt_pk_bf16_f32 %0, %1, %2" : "=v"(u0) : "v"(v[i].x), "v"(v[i].y));
            asm("v_cvt_pk_bf16_f32 %0, %1, %2" : "=v"(u1) : "v"(v[i].z), "v"(v[i].w));
            *reinterpret_cast<uint2*>(&Bf[buf][(chp + 16 * i) * LROW + 4 * qq]) =
                make_uint2(u0, u1);
        }
    };
    auto CONSUME = [&](int buf, int ck) {
        #pragma unroll
        for (int ks = 0; ks < 4; ++ks) {
            const int4 lA = *reinterpret_cast<const int4*>(&labL[ck * CHUNK + ks * 32 + g * 8]);
            const int4 lB = *reinterpret_cast<const int4*>(&labL[ck * CHUNK + ks * 32 + g * 8 + 4]);
            const short8 bf0 = *reinterpret_cast<const short8*>(
                &Bf[buf][((2 * ctg + 0) * 16 + rowid) * LROW + ks * 32 + g * 8]);
            const short8 bf1 = *reinterpret_cast<const short8*>(
                &Bf[buf][((2 * ctg + 1) * 16 + rowid) * LROW + ks * 32 + g * 8]);
            #pragma unroll
            for (int j = 0; j < 3; ++j) {
                const int m = mg + 4 * j;
                if (m < MT) {
                    const int tgt = m * 16 + rowid;
                    unsigned a0 = (lA.x == tgt ? 0x3F80u : 0u) | (lA.y == tgt ? 0x3F800000u : 0u);
                    unsigned a1 = (lA.z == tgt ? 0x3F80u : 0u) | (lA.w == tgt ? 0x3F800000u : 0u);
                    unsigned a2 = (lB.x == tgt ? 0x3F80u : 0u) | (lB.y == tgt ? 0x3F800000u : 0u);
                    unsigned a3 = (lB.z == tgt ? 0x3F80u : 0u) | (lB.w == tgt ? 0x3F800000u : 0u);
                    short8 afrag = __builtin_bit_cast(short8, make_uint4(a0, a1, a2, a3));
                    acc0[j] = __builtin_amdgcn_mfma_f32_16x16x32_bf16(afrag, bf0, acc0[j], 0, 0, 0);
                    acc1[j] = __builtin_amdgcn_mfma_f32_16x16x32_bf16(afrag, bf1, acc1[j], 0, 0, 0);
                }
            }
        }
    };

    issue(0);
    #pragma unroll 1
    for (int ck = 0; ck < NCHK; ++ck) {
        const int cur = ck & 1;
        commit(cur);                        // implicit vmcnt wait on pf
        if (ck + 1 < NCHK) issue(ck + 1);   // next chunk in flight under MFMA
        __syncthreads();                    // single barrier per chunk (dbuf-safe)
        CONSUME(cur, ck);
    }

    // flush: park f32 accs in LDS (reuse Bf), convert+copy linearly as bf16.
    __syncthreads();
    float* fs = reinterpret_cast<float*>(&Bf[0][0]);   // 5120 floats = 20 KB
    #pragma unroll 1
    for (int h = 0; h < 2; ++h) {
        if (ctg == h) {
            #pragma unroll
            for (int j = 0; j < 3; ++j) {
                const int m = mg + 4 * j;
                if (m < MT) {
                    #pragma unroll
                    for (int r = 0; r < 4; ++r) {
                        fs[(m * 16 + g * 4 + r) * 32 + rowid]      = acc0[j][r];
                        fs[(m * 16 + g * 4 + r) * 32 + 16 + rowid] = acc1[j][r];
                    }
                }
            }
        }
        __syncthreads();
        {
            unsigned* du = reinterpret_cast<unsigned*>(
                partial16 + (((size_t)pb * CGN + cg) * 2 + h) * (size_t)K_PAD * 32);
            #pragma unroll
            for (int i = 0; i < 5; ++i) {        // 2560 uints = 5 x 512
                const int idx = tid + i * THR;
                unsigned u;
                asm("v_cvt_pk_bf16_f32 %0, %1, %2"
                    : "=v"(u) : "v"(fs[2 * idx]), "v"(fs[2 * idx + 1]));
                du[idx] = u;
            }
        }
        __syncthreads();
    }
    if (cg == 0)
        for (int i = tid; i < K_PAD; i += THR)
            if (pres[i]) vmask[i] = 1.0f;
}

// ---------------------------------------------------------------------------
// tail: block k. Phase 1: bf16 uint2 reduce over NPB=256 slots (8 chains) +
// L2-normalize (count cancels). Phase 2: text sweep, fused norm + online
// logsumexp. Ticket finalize.
// ---------------------------------------------------------------------------
__global__ __launch_bounds__(256) void tail_kernel(
    const unsigned short* __restrict__ partial16, // [NPB][CGN][2][K_PAD][32]
    const float* __restrict__ text,       // [K][C]
    const float* __restrict__ vmask,      // [K_PAD]
    float* __restrict__ loss_acc,
    unsigned int* __restrict__ ticket,
    float* __restrict__ out,
    int K, int C, int nblocks)
{
    __shared__ float ph[256];
    __shared__ float scr[4][260];
    __shared__ float vm[K_PAD];
    __shared__ float red[5];
    __shared__ float wred[12];
    __shared__ unsigned int lastflag;

    const int k    = blockIdx.x;
    const int tid  = threadIdx.x;
    const int wid  = tid >> 6;
    const int lane = tid & 63;

    if (tid < K_PAD) vm[tid] = vmask[tid];
    __syncthreads();
    const bool valid = (vm[k] > 0.f);

    auto bf4 = [](uint2 u) -> float4 {
        float4 f;
        f.x = __builtin_bit_cast(float, u.x << 16);
        f.y = __builtin_bit_cast(float, u.x & 0xffff0000u);
        f.z = __builtin_bit_cast(float, u.y << 16);
        f.w = __builtin_bit_cast(float, u.y & 0xffff0000u);
        return f;
    };

    float contrib = 0.f;
    if (valid) {
        // phase 1: thread (sg=tid>>6, cq=tid&63) handles channels 4cq..4cq+3
        // c=4cq -> cg=cq>>4, h=(cq>>3)&1, q0=(cq&7)*4
        const int cq = tid & 63;
        const int sg = tid >> 6;
        const size_t gs = (size_t)CGN * 2 * K_PAD * 32;   // shorts per slot
        const unsigned short* pbase = partial16
            + ((size_t)((cq >> 4) * 2 + ((cq >> 3) & 1)) * K_PAD + k) * 32
            + (cq & 7) * 4;
        float4 a0 = {0,0,0,0}, a1 = {0,0,0,0}, a2 = {0,0,0,0}, a3 = {0,0,0,0};
        float4 a4 = {0,0,0,0}, a5 = {0,0,0,0}, a6 = {0,0,0,0}, a7 = {0,0,0,0};
        for (int o = 0; o < NPB; o += 32) {
            a0 += bf4(*(const uint2*)(pbase + (size_t)(o + sg +  0) * gs));
            a1 += bf4(*(const uint2*)(pbase + (size_t)(o + sg +  4) * gs));
            a2 += bf4(*(const uint2*)(pbase + (size_t)(o + sg +  8) * gs));
            a3 += bf4(*(const uint2*)(pbase + (size_t)(o + sg + 12) * gs));
            a4 += bf4(*(const uint2*)(pbase + (size_t)(o + sg + 16) * gs));
            a5 += bf4(*(const uint2*)(pbase + (size_t)(o + sg + 20) * gs));
            a6 += bf4(*(const uint2*)(pbase + (size_t)(o + sg + 24) * gs));
            a7 += bf4(*(const uint2*)(pbase + (size_t)(o + sg + 28) * gs));
        }
        float4 asum = (((a0 + a1) + (a2 + a3)) + ((a4 + a5) + (a6 + a7)));
        *(float4*)&scr[sg][4 * cq] = asum;
        __syncthreads();
        float val = scr[0][tid] + scr[1][tid] + scr[2][tid] + scr[3][tid];

        float v = val * val;
        #pragma unroll
        for (int o = 32; o > 0; o >>= 1) v += __shfl_down(v, o);
        if (lane == 0) red[wid] = v;
        __syncthreads();
        if (tid == 0) {
            float s = red[0] + red[1] + red[2] + red[3];
            red[4] = 1.0f / fmaxf(sqrtf(s), EPSV);
        }
        __syncthreads();
        ph[tid] = val * red[4];
        __syncthreads();

        const float4 pv = *(const float4*)&ph[4 * lane];
        float m = -INFINITY, s = 0.f, skk = 0.f;
        #pragma unroll 1
        for (int gq = 0; gq < K_PAD / 16; ++gq) {
            const int j0 = gq * 16 + wid * 4;
            const float4* t0 = (const float4*)(text + (size_t)(j0 + 0 < K ? j0 + 0 : 0) * C);
            const float4* t1 = (const float4*)(text + (size_t)(j0 + 1 < K ? j0 + 1 : 0) * C);
            const float4* t2 = (const float4*)(text + (size_t)(j0 + 2 < K ? j0 + 2 : 0) * C);
            const float4* t3 = (const float4*)(text + (size_t)(j0 + 3 < K ? j0 + 3 : 0) * C);
            float4 x0 = t0[lane], x1 = t1[lane], x2 = t2[lane], x3 = t3[lane];
            float d0 = pv.x*x0.x + pv.y*x0.y + pv.z*x0.z + pv.w*x0.w;
            float q0 = x0.x*x0.x + x0.y*x0.y + x0.z*x0.z + x0.w*x0.w;
            float d1 = pv.x*x1.x + pv.y*x1.y + pv.z*x1.z + pv.w*x1.w;
            float q1 = x1.x*x1.x + x1.y*x1.y + x1.z*x1.z + x1.w*x1.w;
            float d2 = pv.x*x2.x + pv.y*x2.y + pv.z*x2.z + pv.w*x2.w;
            float q2 = x2.x*x2.x + x2.y*x2.y + x2.z*x2.z + x2.w*x2.w;
            float d3 = pv.x*x3.x + pv.y*x3.y + pv.z*x3.z + pv.w*x3.w;
            float q3 = x3.x*x3.x + x3.y*x3.y + x3.z*x3.z + x3.w*x3.w;
            #pragma unroll
            for (int o = 32; o > 0; o >>= 1) {
                d0 += __shfl_down(d0, o); d1 += __shfl_down(d1, o);
                d2 += __shfl_down(d2, o); d3 += __shfl_down(d3, o);
                q0 += __shfl_down(q0, o); q1 += __shfl_down(q1, o);
                q2 += __shfl_down(q2, o); q3 += __shfl_down(q3, o);
            }
            if (lane == 0) {
                float dd[4] = {d0, d1, d2, d3};
                float qq[4] = {q0, q1, q2, q3};
                #pragma unroll
                for (int r = 0; r < 4; ++r) {
                    int j = j0 + r;
                    float vmj = vm[j];
                    float sim = dd[r] * (10.0f / fmaxf(sqrtf(qq[r]), EPSV));
                    float ms  = vmj * sim - (1.f - vmj) * 1e9f;
                    if (j == k) skk = ms;
                    if (ms > m) { s = s * __expf(m - ms) + 1.f; m = ms; }
                    else        { s += __expf(ms - m); }
                }
            }
        }
        if (lane == 0) { wred[wid*3+0] = m; wred[wid*3+1] = s; wred[wid*3+2] = skk; }
        __syncthreads();
        if (tid == 0) {
            float M = fmaxf(fmaxf(wred[0], wred[3]), fmaxf(wred[6], wred[9]));
            float S = 0.f, SKK = 0.f;
            #pragma unroll
            for (int ww = 0; ww < 4; ++ww) {
                S   += wred[ww*3+1] * __expf(wred[ww*3+0] - M);
                SKK += wred[ww*3+2];
            }
            contrib = M + logf(S) - SKK;      // -logp[k][k]
        }
    }

    if (tid == 0) {
        if (valid) atomicAdd(loss_acc, contrib);
        __threadfence();
        unsigned old = atomicAdd(ticket, 1u);
        lastflag = (old == (unsigned)(nblocks - 1)) ? 1u : 0u;
    }
    __syncthreads();
    if (lastflag) {
        float v = (tid < K_PAD) ? vm[tid] : 0.f;
        #pragma unroll
        for (int o = 32; o > 0; o >>= 1) v += __shfl_down(v, o);
        if (lane == 0) red[wid] = v;
        __syncthreads();
        if (tid == 0) {
            float nv = red[0] + red[1] + red[2] + red[3];
            float total = atomicAdd(loss_acc, 0.0f);   // device-scope read
            out[0] = (nv > 1.f) ? total / fmaxf(nv, 1.f) : 0.f;
        }
    }
}

extern "C" void kernel_launch(void* const* d_in, const int* in_sizes, int n_in,
                              void* d_out, int out_size, void* d_ws, size_t ws_size,
                              hipStream_t stream) {
    const float* feat   = (const float*)d_in[0];
    const int*   labels = (const int*)d_in[1];
    const float* text   = (const float*)d_in[2];
    const int*   ign    = (const int*)d_in[3];

    const int B  = 8;
    const int N  = in_sizes[1];          // 131072
    const int HW = N / B;                // 16384
    const int C  = in_sizes[0] / N;      // 256
    const int K  = in_sizes[2] / C;      // 150

    // workspace: partial16 bf16 ~21 MB (fully overwritten) | vmask | acc | ticket
    unsigned short* partial16 = (unsigned short*)d_ws;
    const size_t p16n = (size_t)NPB * CGN * 2 * K_PAD * 32;
    float*        vmask    = (float*)(partial16 + p16n);
    float*        loss_acc = vmask + K_PAD;
    unsigned int* ticket   = (unsigned int*)(loss_acc + 1);

    hipMemsetAsync(vmask, 0, (K_PAD + 2) * sizeof(float), stream);

    protomm_kernel<<<NPB * CGN, THR, 0, stream>>>(
        feat, labels, ign, partial16, vmask, C, HW);

    tail_kernel<<<K, 256, 0, stream>>>(
        partial16, text, vmask, loss_acc, ticket, (float*)d_out, K, C, K);
}

// Round 14
// 68.334 us; speedup vs baseline: 1.4378x; 1.4378x over previous
//
#include <hip/hip_runtime.h>
#include <math.h>

#define EPSV 1e-12f

typedef __attribute__((ext_vector_type(8))) short short8;
typedef __attribute__((ext_vector_type(4))) float f32x4;

constexpr int MT    = 10;            // m-tiles of 16 -> K_PAD = 160
constexpr int K_PAD = 160;
constexpr int CPB   = 64;            // channels per block
constexpr int CGN   = 4;             // channel groups
constexpr int CHPX  = 256;           // pixels per chunk (8 ksteps)
constexpr int PBPX  = 1024;          // pixels per strip
constexpr int NCHK  = PBPX / CHPX;   // 4 chunks
constexpr int NPB   = 128;           // strips
constexpr int THR   = 512;           // 8 waves
constexpr int LROW  = 264;           // LDS B-row stride in shorts (528 B)

// ---------------------------------------------------------------------------
// protomm: one-hot MFMA GEMM with memcpy-shaped staging.
// Stage: wave w, instr i reads 1 KB CONTIGUOUS from channel row (w+8i)
// (lane l: float4 at px 4l) -- same per-instruction shape as the 6.3 TB/s
// copy ubench; 8 loads/thread in flight. cvt_pk -> ds_write full 512B rows.
// Raw s_barrier + lgkmcnt(0) only: next chunk's loads stay in flight across
// the barrier (no vmcnt(0) drain). Consume: wave (ctg,mg) builds A-frag once
// per m, 2 MFMAs (ct pair). Flush: r7's measured-clean 64B-segment stores
// into 21 MB [pb][K_PAD][C] (<= L2, 4 writers/row -> lines merge, no RMW).
// ---------------------------------------------------------------------------
__global__ __launch_bounds__(THR, 4) void protomm_kernel(
    const float* __restrict__ feat,     // [B,C,HW]
    const int*   __restrict__ labels,   // [B,HW]
    const int*   __restrict__ ign_p,
    float*       __restrict__ partial,  // [NPB][K_PAD][C]
    float*       __restrict__ vmask,    // [K_PAD] pre-zeroed
    int C, int HW)
{
    __shared__ unsigned short Bf[2][CPB * LROW];   // 66 KB
    __shared__ int   labL[PBPX];                   // 4 KB
    __shared__ unsigned char pres[K_PAD];

    const int tid   = threadIdx.x;
    const int w     = tid >> 6;
    const int lane  = tid & 63;
    const int rowid = lane & 15;
    const int g     = lane >> 4;
    const int ctg   = w & 1;            // ct pair {2ctg, 2ctg+1}
    const int mg    = w >> 1;           // m in {mg, mg+4, mg+8<10}

    const int bid = blockIdx.x;
    const int cg  = bid & 3;
    const int pb  = bid >> 2;
    const int b   = pb >> 4;            // 16 strips per image
    const int px0 = (pb & 15) * PBPX;
    const int ig  = *ign_p;

    // per-thread stage source: row (w + 8i), px = 4*lane
    const float* fbase = feat + ((size_t)b * C + cg * CPB + w) * HW + px0 + 4 * lane;

    float4 pf[8];
    auto ISSUE = [&](int ck) {
        #pragma unroll
        for (int i = 0; i < 8; ++i)
            pf[i] = *reinterpret_cast<const float4*>(fbase + (size_t)(8 * i) * HW + ck * CHPX);
    };

    ISSUE(0);                            // loads rolling before label staging

    if (cg == 0)
        for (int i = tid; i < K_PAD; i += THR) pres[i] = 0;
    {
        int l0 = labels[(size_t)b * HW + px0 + tid];
        int l1 = labels[(size_t)b * HW + px0 + THR + tid];
        labL[tid]       = (l0 == ig) ? 0 : l0;
        labL[tid + THR] = (l1 == ig) ? 0 : l1;
    }
    __syncthreads();
    if (cg == 0) {
        int la = labL[tid];
        if ((unsigned)la < (unsigned)K_PAD) pres[la] = 1;
        la = labL[tid + THR];
        if ((unsigned)la < (unsigned)K_PAD) pres[la] = 1;
    }

    f32x4 acc0[3], acc1[3];
    #pragma unroll
    for (int j = 0; j < 3; ++j) {
        acc0[j] = (f32x4){0.f, 0.f, 0.f, 0.f};
        acc1[j] = (f32x4){0.f, 0.f, 0.f, 0.f};
    }

    auto COMMIT = [&](int buf) {
        #pragma unroll
        for (int i = 0; i < 8; ++i) {    // compiler inserts incremental vmcnt
            unsigned u0, u1;
            asm("v_cvt_pk_bf16_f32 %0, %1, %2" : "=v"(u0) : "v"(pf[i].x), "v"(pf[i].y));
            asm("v_cvt_pk_bf16_f32 %0, %1, %2" : "=v"(u1) : "v"(pf[i].z), "v"(pf[i].w));
            *reinterpret_cast<uint2*>(&Bf[buf][(w + 8 * i) * LROW + 4 * lane]) =
                make_uint2(u0, u1);
        }
    };

    auto CONSUME = [&](int buf, int ck) {
        #pragma unroll
        for (int ks = 0; ks < CHPX / 32; ++ks) {
            const int pxb = ck * CHPX + ks * 32 + g * 8;
            const int4 lA = *reinterpret_cast<const int4*>(&labL[pxb]);
            const int4 lB = *reinterpret_cast<const int4*>(&labL[pxb + 4]);
            const short8 bf0 = *reinterpret_cast<const short8*>(
                &Bf[buf][((2 * ctg + 0) * 16 + rowid) * LROW + ks * 32 + g * 8]);
            const short8 bf1 = *reinterpret_cast<const short8*>(
                &Bf[buf][((2 * ctg + 1) * 16 + rowid) * LROW + ks * 32 + g * 8]);
            #pragma unroll
            for (int j = 0; j < 3; ++j) {
                const int m = mg + 4 * j;
                if (m < MT) {
                    const int tgt = m * 16 + rowid;
                    unsigned a0 = (lA.x == tgt ? 0x3F80u : 0u) | (lA.y == tgt ? 0x3F800000u : 0u);
                    unsigned a1 = (lA.z == tgt ? 0x3F80u : 0u) | (lA.w == tgt ? 0x3F800000u : 0u);
                    unsigned a2 = (lB.x == tgt ? 0x3F80u : 0u) | (lB.y == tgt ? 0x3F800000u : 0u);
                    unsigned a3 = (lB.z == tgt ? 0x3F80u : 0u) | (lB.w == tgt ? 0x3F800000u : 0u);
                    short8 afrag = __builtin_bit_cast(short8, make_uint4(a0, a1, a2, a3));
                    acc0[j] = __builtin_amdgcn_mfma_f32_16x16x32_bf16(afrag, bf0, acc0[j], 0, 0, 0);
                    acc1[j] = __builtin_amdgcn_mfma_f32_16x16x32_bf16(afrag, bf1, acc1[j], 0, 0, 0);
                }
            }
        }
    };

    #pragma unroll 1
    for (int ck = 0; ck < NCHK; ++ck) {
        const int cur = ck & 1;
        COMMIT(cur);                         // waits only its own loads
        if (ck + 1 < NCHK) ISSUE(ck + 1);    // 8 KB/wave in flight across barrier
        asm volatile("s_waitcnt lgkmcnt(0)" ::: "memory");   // my ds_writes done
        __builtin_amdgcn_sched_barrier(0);
        __builtin_amdgcn_s_barrier();        // raw: loads NOT drained
        __builtin_amdgcn_sched_barrier(0);
        CONSUME(cur, ck);
        __builtin_amdgcn_sched_barrier(0);
        __builtin_amdgcn_s_barrier();        // all reads of buf done before rewrite
        __builtin_amdgcn_sched_barrier(0);
    }

    // flush: r7's measured-clean pattern (complete accs, 64B-segment stores)
    {
        float* dst = partial + (size_t)pb * K_PAD * C + cg * CPB;
        #pragma unroll
        for (int j = 0; j < 3; ++j) {
            const int m = mg + 4 * j;
            if (m < MT) {
                #pragma unroll
                for (int r = 0; r < 4; ++r) {
                    const int cls = m * 16 + g * 4 + r;
                    dst[(size_t)cls * C + (2 * ctg + 0) * 16 + rowid] = acc0[j][r];
                    dst[(size_t)cls * C + (2 * ctg + 1) * 16 + rowid] = acc1[j][r];
                }
            }
        }
    }
    if (cg == 0)
        for (int i = tid; i < K_PAD; i += THR)
            if (pres[i]) vmask[i] = 1.0f;
}

// ---------------------------------------------------------------------------
// tail: block k. Phase 1: float4 reduce over NPB=128 slots (8 chains) +
// L2-normalize (count cancels). Phase 2: text sweep, fused norm + online
// logsumexp. Ticket finalize.
// ---------------------------------------------------------------------------
__global__ __launch_bounds__(256) void tail_kernel(
    const float* __restrict__ partial,    // [NPB][K_PAD][C]
    const float* __restrict__ text,       // [K][C]
    const float* __restrict__ vmask,      // [K_PAD]
    float* __restrict__ loss_acc,
    unsigned int* __restrict__ ticket,
    float* __restrict__ out,
    int K, int C, int nblocks)
{
    __shared__ float ph[256];
    __shared__ float scr[4][260];
    __shared__ float vm[K_PAD];
    __shared__ float red[5];
    __shared__ float wred[12];
    __shared__ unsigned int lastflag;

    const int k    = blockIdx.x;
    const int tid  = threadIdx.x;
    const int wid  = tid >> 6;
    const int lane = tid & 63;

    if (tid < K_PAD) vm[tid] = vmask[tid];
    __syncthreads();
    const bool valid = (vm[k] > 0.f);

    float contrib = 0.f;
    if (valid) {
        const int cq = tid & 63;
        const int sg = tid >> 6;
        const size_t gs = (size_t)K_PAD * C;
        const float* pbase = partial + (size_t)k * C + 4 * cq;
        float4 a0 = {0,0,0,0}, a1 = {0,0,0,0}, a2 = {0,0,0,0}, a3 = {0,0,0,0};
        float4 a4 = {0,0,0,0}, a5 = {0,0,0,0}, a6 = {0,0,0,0}, a7 = {0,0,0,0};
        for (int o = 0; o < NPB; o += 32) {
            a0 += *(const float4*)(pbase + (size_t)(o + sg +  0) * gs);
            a1 += *(const float4*)(pbase + (size_t)(o + sg +  4) * gs);
            a2 += *(const float4*)(pbase + (size_t)(o + sg +  8) * gs);
            a3 += *(const float4*)(pbase + (size_t)(o + sg + 12) * gs);
            a4 += *(const float4*)(pbase + (size_t)(o + sg + 16) * gs);
            a5 += *(const float4*)(pbase + (size_t)(o + sg + 20) * gs);
            a6 += *(const float4*)(pbase + (size_t)(o + sg + 24) * gs);
            a7 += *(const float4*)(pbase + (size_t)(o + sg + 28) * gs);
        }
        float4 asum = (((a0 + a1) + (a2 + a3)) + ((a4 + a5) + (a6 + a7)));
        *(float4*)&scr[sg][4 * cq] = asum;
        __syncthreads();
        float val = scr[0][tid] + scr[1][tid] + scr[2][tid] + scr[3][tid];

        float v = val * val;
        #pragma unroll
        for (int o = 32; o > 0; o >>= 1) v += __shfl_down(v, o);
        if (lane == 0) red[wid] = v;
        __syncthreads();
        if (tid == 0) {
            float s = red[0] + red[1] + red[2] + red[3];
            red[4] = 1.0f / fmaxf(sqrtf(s), EPSV);
        }
        __syncthreads();
        ph[tid] = val * red[4];
        __syncthreads();

        const float4 pv = *(const float4*)&ph[4 * lane];
        float m = -INFINITY, s = 0.f, skk = 0.f;
        #pragma unroll 1
        for (int gq = 0; gq < K_PAD / 16; ++gq) {
            const int j0 = gq * 16 + wid * 4;
            const float4* t0 = (const float4*)(text + (size_t)(j0 + 0 < K ? j0 + 0 : 0) * C);
            const float4* t1 = (const float4*)(text + (size_t)(j0 + 1 < K ? j0 + 1 : 0) * C);
            const float4* t2 = (const float4*)(text + (size_t)(j0 + 2 < K ? j0 + 2 : 0) * C);
            const float4* t3 = (const float4*)(text + (size_t)(j0 + 3 < K ? j0 + 3 : 0) * C);
            float4 x0 = t0[lane], x1 = t1[lane], x2 = t2[lane], x3 = t3[lane];
            float d0 = pv.x*x0.x + pv.y*x0.y + pv.z*x0.z + pv.w*x0.w;
            float q0 = x0.x*x0.x + x0.y*x0.y + x0.z*x0.z + x0.w*x0.w;
            float d1 = pv.x*x1.x + pv.y*x1.y + pv.z*x1.z + pv.w*x1.w;
            float q1 = x1.x*x1.x + x1.y*x1.y + x1.z*x1.z + x1.w*x1.w;
            float d2 = pv.x*x2.x + pv.y*x2.y + pv.z*x2.z + pv.w*x2.w;
            float q2 = x2.x*x2.x + x2.y*x2.y + x2.z*x2.z + x2.w*x2.w;
            float d3 = pv.x*x3.x + pv.y*x3.y + pv.z*x3.z + pv.w*x3.w;
            float q3 = x3.x*x3.x + x3.y*x3.y + x3.z*x3.z + x3.w*x3.w;
            #pragma unroll
            for (int o = 32; o > 0; o >>= 1) {
                d0 += __shfl_down(d0, o); d1 += __shfl_down(d1, o);
                d2 += __shfl_down(d2, o); d3 += __shfl_down(d3, o);
                q0 += __shfl_down(q0, o); q1 += __shfl_down(q1, o);
                q2 += __shfl_down(q2, o); q3 += __shfl_down(q3, o);
            }
            if (lane == 0) {
                float dd[4] = {d0, d1, d2, d3};
                float qq[4] = {q0, q1, q2, q3};
                #pragma unroll
                for (int r = 0; r < 4; ++r) {
                    int j = j0 + r;
                    float vmj = vm[j];
                    float sim = dd[r] * (10.0f / fmaxf(sqrtf(qq[r]), EPSV));
                    float ms  = vmj * sim - (1.f - vmj) * 1e9f;
                    if (j == k) skk = ms;
                    if (ms > m) { s = s * __expf(m - ms) + 1.f; m = ms; }
                    else        { s += __expf(ms - m); }
                }
            }
        }
        if (lane == 0) { wred[wid*3+0] = m; wred[wid*3+1] = s; wred[wid*3+2] = skk; }
        __syncthreads();
        if (tid == 0) {
            float M = fmaxf(fmaxf(wred[0], wred[3]), fmaxf(wred[6], wred[9]));
            float S = 0.f, SKK = 0.f;
            #pragma unroll
            for (int ww = 0; ww < 4; ++ww) {
                S   += wred[ww*3+1] * __expf(wred[ww*3+0] - M);
                SKK += wred[ww*3+2];
            }
            contrib = M + logf(S) - SKK;      // -logp[k][k]
        }
    }

    if (tid == 0) {
        if (valid) atomicAdd(loss_acc, contrib);
        __threadfence();
        unsigned old = atomicAdd(ticket, 1u);
        lastflag = (old == (unsigned)(nblocks - 1)) ? 1u : 0u;
    }
    __syncthreads();
    if (lastflag) {
        float v = (tid < K_PAD) ? vm[tid] : 0.f;
        #pragma unroll
        for (int o = 32; o > 0; o >>= 1) v += __shfl_down(v, o);
        if (lane == 0) red[wid] = v;
        __syncthreads();
        if (tid == 0) {
            float nv = red[0] + red[1] + red[2] + red[3];
            float total = atomicAdd(loss_acc, 0.0f);   // device-scope read
            out[0] = (nv > 1.f) ? total / fmaxf(nv, 1.f) : 0.f;
        }
    }
}

extern "C" void kernel_launch(void* const* d_in, const int* in_sizes, int n_in,
                              void* d_out, int out_size, void* d_ws, size_t ws_size,
                              hipStream_t stream) {
    const float* feat   = (const float*)d_in[0];
    const int*   labels = (const int*)d_in[1];
    const float* text   = (const float*)d_in[2];
    const int*   ign    = (const int*)d_in[3];

    const int B  = 8;
    const int N  = in_sizes[1];          // 131072
    const int HW = N / B;                // 16384
    const int C  = in_sizes[0] / N;      // 256
    const int K  = in_sizes[2] / C;      // 150

    // workspace: partial [NPB][K_PAD][C] ~21 MB (fully overwritten) | vmask | acc | ticket
    float*        partial  = (float*)d_ws;
    float*        vmask    = partial + (size_t)NPB * K_PAD * C;
    float*        loss_acc = vmask + K_PAD;
    unsigned int* ticket   = (unsigned int*)(loss_acc + 1);

    hipMemsetAsync(vmask, 0, (K_PAD + 2) * sizeof(float), stream);

    protomm_kernel<<<NPB * CGN, THR, 0, stream>>>(
        feat, labels, ign, partial, vmask, C, HW);

    tail_kernel<<<K, 256, 0, stream>>>(
        partial, text, vmask, loss_acc, ticket, (float*)d_out, K, C, K);
}